// Round 1
// baseline (719.875 us; speedup 1.0000x reference)
//
#include <hip/hip_runtime.h>
#include <math.h>

// RNN scan: h_t = tanh(h_{t-1} @ Whh + b_hh + x_t * Wxh + b_xh), out = h_T @ Wout + b_out
// B=16384 rows, T=1024 steps, H=32 hidden.
//
// Design (round 1): pure-VALU fp32.
//  - lane j (tid&31) owns h_j of one row; each wave = 2 rows (one per 32-lane half).
//  - Whh column j kept in 32 VGPRs per lane, loaded once (reused 1024 steps).
//  - per-step h broadcast via LDS: 1 ds_write_b32 + 8 broadcast ds_read_b128,
//    wave-synchronous (each half only touches its own row -> no __syncthreads).
//  - x staged in LDS in 64-step chunks, consumed 4 steps per b128 broadcast read.
//  - 1024 persistent blocks x 256 thr (4 blocks/CU, all resident), 2 row-groups each.

constexpr int Bsz  = 16384;
constexpr int Tlen = 1024;
constexpr int Hdim = 32;
constexpr int ROWS_PER_BLOCK = 8;            // 4 waves * 2 rows
constexpr int NBLOCKS = 1024;
constexpr int NGROUPS = Bsz / (ROWS_PER_BLOCK * NBLOCKS);   // 2

__device__ __forceinline__ float fast_tanh(float x) {
    // tanh(x) = sign(x) * (1 - e) / (1 + e),  e = exp(-2|x|)  -- no overflow path
    float ax = __builtin_fabsf(x);
    float e  = __builtin_amdgcn_exp2f(ax * -2.8853900817779268f); // exp(-2ax)
    float num = 1.0f - e;
    float den = 1.0f + e;
    float r = num * __builtin_amdgcn_rcpf(den);
    return __builtin_copysignf(r, x);
}

__global__ __launch_bounds__(256, 4)
void rnn_scan_kernel(const float* __restrict__ x,    // [B,T]
                     const float* __restrict__ Wxh,  // [1,H]
                     const float* __restrict__ b_xh, // [H]
                     const float* __restrict__ Whh,  // [H,H] row-major (i,j)
                     const float* __restrict__ b_hh, // [H]
                     const float* __restrict__ Wout, // [H,1]
                     const float* __restrict__ b_out,// [1]
                     float* __restrict__ out)        // [B,1]
{
    __shared__ float hsh[ROWS_PER_BLOCK][Hdim];  // per-row current h (128B rows)
    __shared__ float xsh[4][2][64];              // per wave, per half: 64-step x chunk

    const int tid  = threadIdx.x;
    const int wave = tid >> 6;
    const int half = (tid >> 5) & 1;
    const int j    = tid & 31;
    const int rl   = wave * 2 + half;            // local row 0..7

    // Per-lane constants (reused across all steps / groups)
    float wc[Hdim];                              // Whh[:, j] -> 32 VGPRs
    #pragma unroll
    for (int i = 0; i < Hdim; ++i) wc[i] = Whh[i * Hdim + j];
    const float bconst = b_hh[j] + b_xh[j];
    const float wxh_j  = Wxh[j];
    const float wout_j = Wout[j];
    const float bout   = b_out[0];

    #pragma unroll 1
    for (int g = 0; g < NGROUPS; ++g) {
        const int row = (g * NBLOCKS + blockIdx.x) * ROWS_PER_BLOCK + rl;
        const float* xr = x + (size_t)row * Tlen;

        hsh[rl][j] = 0.0f;                       // h0 = 0
        float hmine = 0.0f;

        #pragma unroll 1
        for (int tc = 0; tc < Tlen; tc += 64) {
            // Stage this wave's x chunk: each half loads 64 floats of its own row.
            {
                float2 v = ((const float2*)(xr + tc))[j];
                xsh[wave][half][2 * j]     = v.x;
                xsh[wave][half][2 * j + 1] = v.y;
            }
            // wave-synchronous: same wave wrote, same wave reads (lgkmcnt ordering)

            #pragma unroll 1
            for (int tq = 0; tq < 64; tq += 4) {
                float4 xq = ((const float4*)xsh[wave][half])[tq >> 2];
                float xs[4] = {xq.x, xq.y, xq.z, xq.w};
                #pragma unroll
                for (int u = 0; u < 4; ++u) {
                    // 4 accumulator chains to cut FMA latency exposure
                    float a0 = fmaf(xs[u], wxh_j, bconst);
                    float a1 = 0.0f, a2 = 0.0f, a3 = 0.0f;
                    const float4* h4 = (const float4*)hsh[rl];
                    #pragma unroll
                    for (int q = 0; q < 8; q += 4) {
                        float4 hb0 = h4[q + 0];
                        float4 hb1 = h4[q + 1];
                        float4 hb2 = h4[q + 2];
                        float4 hb3 = h4[q + 3];
                        a0 = fmaf(hb0.x, wc[4*q + 0],  a0);
                        a0 = fmaf(hb0.y, wc[4*q + 1],  a0);
                        a0 = fmaf(hb0.z, wc[4*q + 2],  a0);
                        a0 = fmaf(hb0.w, wc[4*q + 3],  a0);
                        a1 = fmaf(hb1.x, wc[4*q + 4],  a1);
                        a1 = fmaf(hb1.y, wc[4*q + 5],  a1);
                        a1 = fmaf(hb1.z, wc[4*q + 6],  a1);
                        a1 = fmaf(hb1.w, wc[4*q + 7],  a1);
                        a2 = fmaf(hb2.x, wc[4*q + 8],  a2);
                        a2 = fmaf(hb2.y, wc[4*q + 9],  a2);
                        a2 = fmaf(hb2.z, wc[4*q + 10], a2);
                        a2 = fmaf(hb2.w, wc[4*q + 11], a2);
                        a3 = fmaf(hb3.x, wc[4*q + 12], a3);
                        a3 = fmaf(hb3.y, wc[4*q + 13], a3);
                        a3 = fmaf(hb3.z, wc[4*q + 14], a3);
                        a3 = fmaf(hb3.w, wc[4*q + 15], a3);
                    }
                    float acc = (a0 + a1) + (a2 + a3);
                    hmine = fast_tanh(acc);
                    hsh[rl][j] = hmine;          // publish h_j for next step
                }
            }
        }

        // out[row] = sum_j h_j * Wout[j] + b_out  (reduce within each 32-lane half)
        float v = hmine * wout_j;
        #pragma unroll
        for (int off = 16; off >= 1; off >>= 1)
            v += __shfl_xor(v, off, 64);
        if (j == 0) out[row] = v + bout;
    }
}

extern "C" void kernel_launch(void* const* d_in, const int* in_sizes, int n_in,
                              void* d_out, int out_size, void* d_ws, size_t ws_size,
                              hipStream_t stream) {
    const float* x     = (const float*)d_in[0];
    const float* Wxh   = (const float*)d_in[1];
    const float* b_xh  = (const float*)d_in[2];
    const float* Whh   = (const float*)d_in[3];
    const float* b_hh  = (const float*)d_in[4];
    const float* Wout  = (const float*)d_in[5];
    const float* b_out = (const float*)d_in[6];
    float* out = (float*)d_out;

    rnn_scan_kernel<<<NBLOCKS, 256, 0, stream>>>(x, Wxh, b_xh, Whh, b_hh, Wout,
                                                 b_out, out);
}